// Round 3
// baseline (455.612 us; speedup 1.0000x reference)
//
#include <hip/hip_runtime.h>
#include <stdint.h>

typedef unsigned short ushort_t;
typedef __attribute__((ext_vector_type(8))) short short8;
typedef __attribute__((ext_vector_type(4))) float floatx4;

#define B_    32
#define C_    256
#define O_    256
#define HID_  65
#define HW_   4096
#define KDIM  2304          // C_ * 9
#define XP_H  66            // padded spatial edge
#define XPAD_ELEMS ((size_t)B_ * XP_H * XP_H * C_)   // 35,684,352 bf16
#define WAGG_ELEMS ((size_t)B_ * O_ * KDIM)          // 18,874,368 bf16

static __device__ __forceinline__ unsigned short f2bf(float f) {
  unsigned u = __float_as_uint(f);
  u += 0x7fffu + ((u >> 16) & 1u);        // RNE
  return (unsigned short)(u >> 16);
}

static __device__ __forceinline__ void gld_lds16(const void* g, void* l) {
  // async global->LDS, 16B/lane; LDS dest = wave-uniform base + lane*16
  __builtin_amdgcn_global_load_lds((__attribute__((address_space(1))) void*)(g),
                                   (__attribute__((address_space(3))) void*)(l),
                                   16, 0, 0);
}

// -------------------------------------------------------------- border ------
// zero only the pad borders of xpad (4.3 MB); interior overwritten by pad.
// grid (B_, 4): p=0 top row, 1 bottom row, 2 left col, 3 right col.
__global__ void border_kernel(ushort_t* __restrict__ xpad) {
  const int b = blockIdx.x, p = blockIdx.y, t = threadIdx.x;
  uint4 z = {0u, 0u, 0u, 0u};
  uint4* base = (uint4*)(xpad + (size_t)b * XP_H * XP_H * C_);
  // row stride = 66*256 shorts = 2112 uint4; w stride = 32 uint4
  if (p == 0) {
    for (int i = t; i < 2112; i += 256) base[i] = z;
  } else if (p == 1) {
    for (int i = t; i < 2112; i += 256) base[(size_t)65 * 2112 + i] = z;
  } else if (p == 2) {
    for (int i = t; i < 64 * 32; i += 256) {
      const int h = 1 + (i >> 5), s = i & 31;
      base[(size_t)h * 2112 + s] = z;
    }
  } else {
    for (int i = t; i < 64 * 32; i += 256) {
      const int h = 1 + (i >> 5), s = i & 31;
      base[(size_t)h * 2112 + 65 * 32 + s] = z;
    }
  }
}

// ----------------------------------------------------------------- pad ------
// xpad[b][h+1][w+1][c] (bf16, HWC) from x[b][c][h][w] (fp32, CHW), PLUS
// pooling partials partial[hwT][b*C+c]. 16B global loads + 16B global stores;
// all LDS traffic <=2-way bank aliased (free, m136).
__global__ void pad_kernel(const float* __restrict__ x, ushort_t* __restrict__ xpad,
                           float* __restrict__ partial) {
  __shared__ float tile[64][65];                   // bank(c,hw) = (c+hw)%32
  const int hwT = blockIdx.x, cT = blockIdx.y, b = blockIdx.z;
  const int t = threadIdx.x;
  const int hw0 = hwT * 64, c0 = cT * 64;
  const float* src = x + ((size_t)(b * C_ + c0)) * HW_ + hw0;

  // load: thread t -> w4 = t&15 (16B chunk), cg = t>>4; 4 iters x 16 c-rows
  const int w4 = t & 15, cg = t >> 4;
#pragma unroll
  for (int i = 0; i < 4; ++i) {
    const int ci = cg + i * 16;
    const float4 v = *(const float4*)(src + (size_t)ci * HW_ + w4 * 4);
    tile[ci][w4 * 4 + 0] = v.x;                    // banks (ci+4w4+j)%32: 2-way
    tile[ci][w4 * 4 + 1] = v.y;
    tile[ci][w4 * 4 + 2] = v.z;
    tile[ci][w4 * 4 + 3] = v.w;
  }
  __syncthreads();

  // pooling partial: threads 0..63 own one c each (2-way banks, free)
  if (t < 64) {
    float s = 0.f;
#pragma unroll
    for (int i = 0; i < 64; ++i) s += tile[t][i];
    partial[(size_t)hwT * (B_ * C_) + b * C_ + c0 + t] = s;
  }

  // store: thread t -> hwi = (t>>3)+32*i, s = t&7 (8 consecutive c = 16B)
  const int s8 = (t & 7) * 8, hb = t >> 3;
#pragma unroll
  for (int i = 0; i < 2; ++i) {
    const int hwi = hb + 32 * i;
    const int hw = hw0 + hwi;
    const int h = hw >> 6, w = hw & 63;
    ushort_t v[8];
#pragma unroll
    for (int j = 0; j < 8; ++j) v[j] = f2bf(tile[s8 + j][hwi]);  // 2-way banks
    *(uint4*)(xpad + (((size_t)b * XP_H + (h + 1)) * XP_H + (w + 1)) * C_ + c0 + s8) =
        *(const uint4*)v;
  }
}

// ---------------------------------------------------------------- attn ------
__global__ void attn_kernel(const float* __restrict__ partial,
                            const float* __restrict__ w1,
                            const float* __restrict__ w2,
                            const float* __restrict__ b2,
                            float* __restrict__ attn) {
  __shared__ float sp[C_];
  __shared__ float sh[HID_];
  const int b = blockIdx.x, t = threadIdx.x;
  {
    float s = 0.f;
#pragma unroll
    for (int i = 0; i < 64; ++i) s += partial[(size_t)i * (B_ * C_) + b * C_ + t];
    sp[t] = s * (1.f / 4096.f);
  }
  __syncthreads();
  if (t < HID_) {
    float a = 0.f;
    for (int c = 0; c < C_; ++c) a += sp[c] * w1[t * C_ + c];
    sh[t] = fmaxf(a, 0.f);
  }
  __syncthreads();
  float lg[4];
#pragma unroll
  for (int k = 0; k < 4; ++k) {
    float a = b2[k * O_ + t];
    for (int j = 0; j < HID_; ++j) a += sh[j] * w2[(k * O_ + t) * HID_ + j];
    lg[k] = a * 2.0f;                              // / TEMP (0.5)
  }
  float mx = fmaxf(fmaxf(lg[0], lg[1]), fmaxf(lg[2], lg[3]));
  float e0 = expf(lg[0] - mx), e1 = expf(lg[1] - mx);
  float e2 = expf(lg[2] - mx), e3 = expf(lg[3] - mx);
  float inv = 1.f / (e0 + e1 + e2 + e3);
  attn[(b * 4 + 0) * O_ + t] = e0 * inv;
  attn[(b * 4 + 1) * O_ + t] = e1 * inv;
  attn[(b * 4 + 2) * O_ + t] = e2 * inv;
  attn[(b * 4 + 3) * O_ + t] = e3 * inv;
}

// ----------------------------------------------------------------- agg ------
// wagg[b][o][ck], ck = tap*256 + c. grid (O_, 4 b-groups); thread t owns
// (tap = t>>5, c = (t&31)*8 .. +7) -> one uint4 store per (b): 512B/32 lanes.
__global__ void agg_kernel(const float* __restrict__ attn,
                           const float* __restrict__ wt,
                           ushort_t* __restrict__ wagg) {
  const int o = blockIdx.x, bg = blockIdx.y;
  const int t = threadIdx.x;
  const int n = t >> 5;                            // tap 0..7 (tap 8 handled below)
  const int c8 = (t & 31) * 8;
  // thread covers taps n and (n==0 ? 8 : none)? No: 9 taps, 8 groups ->
  // group n handles tap n; tap 8 handled by ALL groups for their c-range? 
  // Simpler: loop taps n and n+8 when n==0. Instead: each thread handles
  // taps {n, 8} is redundant. Use: tap = n for n<8 plus a second pass for tap 8
  // done by group 0 lanes? Cleanest: iterate tp in {n, 8} but only group 0
  // does tp=8's store... that serializes. Use 288 threads? Not multiple of 64.
  // Chosen: all 8 groups do tap n; tap 8 done by groups via second loop with
  // group-stride over b (8 groups x 4 b each? b range is 8 here).
  float wr[4][8];
#pragma unroll
  for (int k = 0; k < 4; ++k) {
    const float* base = wt + (size_t)(k * O_ + o) * KDIM + n;
#pragma unroll
    for (int j = 0; j < 8; ++j) wr[k][j] = base[(size_t)(c8 + j) * 9];
  }
  // tap-8 weights for the b's this group will cover (group g covers b-sub g)
  float wr8[4][8];
#pragma unroll
  for (int k = 0; k < 4; ++k) {
    const float* base = wt + (size_t)(k * O_ + o) * KDIM + 8;
#pragma unroll
    for (int j = 0; j < 8; ++j) wr8[k][j] = base[(size_t)(c8 + j) * 9];
  }
#pragma unroll
  for (int bi = 0; bi < 8; ++bi) {
    const int b = bg * 8 + bi;
    const float a0 = attn[(b * 4 + 0) * O_ + o];
    const float a1 = attn[(b * 4 + 1) * O_ + o];
    const float a2 = attn[(b * 4 + 2) * O_ + o];
    const float a3 = attn[(b * 4 + 3) * O_ + o];
    ushort_t* dst = wagg + (size_t)(b * O_ + o) * KDIM;
    ushort_t v[8];
#pragma unroll
    for (int j = 0; j < 8; ++j)
      v[j] = f2bf(a0 * wr[0][j] + a1 * wr[1][j] + a2 * wr[2][j] + a3 * wr[3][j]);
    *(uint4*)(dst + n * C_ + c8) = *(const uint4*)v;
    // tap 8: group (bi) of this block writes it for b (one group per b)
    if (n == bi) {
      ushort_t v8[8];
#pragma unroll
      for (int j = 0; j < 8; ++j)
        v8[j] = f2bf(a0 * wr8[0][j] + a1 * wr8[1][j] + a2 * wr8[2][j] + a3 * wr8[3][j]);
      *(uint4*)(dst + 8 * C_ + c8) = *(const uint4*)v8;
    }
  }
}

// ---------------------------------------------------------------- gemm ------
// unchanged from round 2: 128x128 tile, BK=64, global_load_lds w=16,
// XOR slot swizzle (phys = logical ^ (row&7)), 888 TF plateau.
__global__ __launch_bounds__(256) void gemm_kernel(const ushort_t* __restrict__ xpad,
                                                   const ushort_t* __restrict__ wagg,
                                                   float* __restrict__ out) {
  __shared__ short lA[128 * 64];                   // 16 KB
  __shared__ short lB[128 * 64];                   // 16 KB

  const int hwT = blockIdx.x;
  const int oT  = blockIdx.y;
  const int b   = blockIdx.z;
  const int t    = threadIdx.x;
  const int lane = t & 63;
  const int wv   = t >> 6;

  const int hwBase = hwT << 7;
  const int h0     = hwT << 1;
  const int oBase  = oT << 7;

  const int rS = lane >> 3;
  const int pS = lane & 7;
  size_t aG[4], bG[4];
  int ldsOff[4];
#pragma unroll
  for (int q = 0; q < 4; ++q) {
    const int row = wv * 32 + q * 8 + rS;
    const int lch = pS ^ (row & 7);
    aG[q] = (size_t)(b * O_ + oBase + row) * KDIM + lch * 8;
    const int hl = row >> 6, wl2 = row & 63;
    bG[q] = ((size_t)(b * XP_H + h0 + hl) * XP_H + wl2) * C_ + lch * 8;
    ldsOff[q] = (wv * 32 + q * 8) * 64;
  }

  const int lm   = lane & 15;
  const int quad = lane >> 4;
  const int mW = (wv & 1) << 6;
  const int nW = (wv >> 1) << 6;
  int aOff[2][4], bOff[2][4];
#pragma unroll
  for (int h = 0; h < 2; ++h)
#pragma unroll
    for (int i = 0; i < 4; ++i) {
      const int ps = ((h * 4 + quad) ^ (lm & 7)) * 8;
      aOff[h][i] = (mW + i * 16 + lm) * 64 + ps;
      bOff[h][i] = (nW + i * 16 + lm) * 64 + ps;
    }

  floatx4 acc[4][4] = {};

  for (int tap = 0; tap < 9; ++tap) {
    const int toff = (tap / 3) * XP_H + (tap % 3);
#pragma unroll 1
    for (int c0 = 0; c0 < C_; c0 += 64) {
      const int kk = tap * C_ + c0;
      __syncthreads();
#pragma unroll
      for (int q = 0; q < 4; ++q) {
        gld_lds16(wagg + aG[q] + kk, lA + ldsOff[q]);
        gld_lds16(xpad + bG[q] + (size_t)toff * C_ + c0, lB + ldsOff[q]);
      }
      __builtin_amdgcn_s_waitcnt(0x0f70);          // vmcnt(0)
      __syncthreads();

#pragma unroll
      for (int h = 0; h < 2; ++h) {
        short8 af[4], bf[4];
#pragma unroll
        for (int i = 0; i < 4; ++i) af[i] = *(const short8*)(lA + aOff[h][i]);
#pragma unroll
        for (int i = 0; i < 4; ++i) bf[i] = *(const short8*)(lB + bOff[h][i]);
#pragma unroll
        for (int mi = 0; mi < 4; ++mi)
#pragma unroll
          for (int ni = 0; ni < 4; ++ni)
            acc[mi][ni] = __builtin_amdgcn_mfma_f32_16x16x32_bf16(
                af[mi], bf[ni], acc[mi][ni], 0, 0, 0);
      }
    }
  }

  const size_t outBase = (size_t)b * O_ * HW_;
#pragma unroll
  for (int mi = 0; mi < 4; ++mi) {
#pragma unroll
    for (int ni = 0; ni < 4; ++ni) {
      const int hw = hwBase + nW + ni * 16 + lm;
#pragma unroll
      for (int r = 0; r < 4; ++r) {
        const int o = oBase + mW + mi * 16 + quad * 4 + r;
        out[outBase + (size_t)o * HW_ + hw] = acc[mi][ni][r];
      }
    }
  }
}

// -------------------------------------------------------------- launch ------
extern "C" void kernel_launch(void* const* d_in, const int* in_sizes, int n_in,
                              void* d_out, int out_size, void* d_ws, size_t ws_size,
                              hipStream_t stream) {
  const float* x  = (const float*)d_in[0];   // [32,256,64,64]
  const float* w1 = (const float*)d_in[1];   // [65,256]
  const float* w2 = (const float*)d_in[2];   // [1024,65]
  const float* b2 = (const float*)d_in[3];   // [1024]
  const float* wt = (const float*)d_in[4];   // [4,256,256,3,3]
  float* out = (float*)d_out;                // [32,256,64,64]

  char* ws = (char*)d_ws;
  ushort_t* xpad = (ushort_t*)ws;                                  // 71.4 MB
  ushort_t* wagg = (ushort_t*)(ws + XPAD_ELEMS * 2);               // 37.7 MB
  float* partial = (float*)(ws + XPAD_ELEMS * 2 + WAGG_ELEMS * 2); // 2 MB
  float* attn    = partial + 64 * B_ * C_;                         // 128 KB

  border_kernel<<<dim3(B_, 4), 256, 0, stream>>>(xpad);
  pad_kernel<<<dim3(64, 4, B_), 256, 0, stream>>>(x, xpad, partial);
  attn_kernel<<<B_, 256, 0, stream>>>(partial, w1, w2, b2, attn);
  agg_kernel<<<dim3(O_, 4), 256, 0, stream>>>(attn, wt, wagg);
  gemm_kernel<<<dim3(32, 2, B_), 256, 0, stream>>>(xpad, wagg, out);
}